// Round 1
// baseline (403.894 us; speedup 1.0000x reference)
//
#include <hip/hip_runtime.h>
#include <hip/hip_bf16.h>
#include <stdint.h>

// ---------- types ----------
typedef __attribute__((ext_vector_type(8))) __bf16 bf16x8;
typedef __attribute__((ext_vector_type(4))) float f32x4;
typedef __attribute__((ext_vector_type(8))) unsigned short ushort8;

typedef const void __attribute__((address_space(1))) gv_t;
typedef void __attribute__((address_space(3))) lv_t;

#define GL16(g, l) __builtin_amdgcn_global_load_lds((gv_t*)(g), (lv_t*)(l), 16, 0, 0)

// f32 -> bf16 bits, round-to-nearest-even (matches HW conversion; inputs finite)
__device__ __forceinline__ unsigned short f2bf(float f) {
    unsigned int u = __float_as_uint(f);
    u += 0x7fffu + ((u >> 16) & 1u);
    return (unsigned short)(u >> 16);
}

// ---------- kernel 1: per-group int4 quant-dequant of W, output bf16 bits ----------
// One thread = one group of 8 along in_features. Must match numpy bitwise in f32:
// scale = max(max|w|/7, 1e-8); q = clip(rint(w/scale), -7, 7); d = q*scale.
__global__ void __launch_bounds__(256) qdq_weight(const float* __restrict__ w,
                                                  unsigned short* __restrict__ wb,
                                                  int n_groups) {
    int g = blockIdx.x * 256 + threadIdx.x;
    if (g >= n_groups) return;
    const float4* p = (const float4*)w + (size_t)g * 2;
    float4 v0 = p[0], v1 = p[1];
    float t[8] = {v0.x, v0.y, v0.z, v0.w, v1.x, v1.y, v1.z, v1.w};
    float amax = 0.0f;
#pragma unroll
    for (int j = 0; j < 8; ++j) amax = fmaxf(amax, fabsf(t[j]));
    float scale = fmaxf(amax / 7.0f, 1e-8f);
    ushort8 o;
#pragma unroll
    for (int j = 0; j < 8; ++j) {
        float q = rintf(t[j] / scale);
        q = fminf(fmaxf(q, -7.0f), 7.0f);
        o[j] = f2bf(q * scale);
    }
    *((ushort8*)wb + g) = o;
}

// ---------- kernel 2: f32 -> bf16 cast of x (vectorized 8/thread) ----------
__global__ void __launch_bounds__(256) cvt_bf16(const float* __restrict__ x,
                                                unsigned short* __restrict__ xb,
                                                int n8) {
    int i = blockIdx.x * 256 + threadIdx.x;
    if (i >= n8) return;
    const float4* p = (const float4*)x + (size_t)i * 2;
    float4 v0 = p[0], v1 = p[1];
    ushort8 o;
    o[0] = f2bf(v0.x); o[1] = f2bf(v0.y); o[2] = f2bf(v0.z); o[3] = f2bf(v0.w);
    o[4] = f2bf(v1.x); o[5] = f2bf(v1.y); o[6] = f2bf(v1.z); o[7] = f2bf(v1.w);
    *((ushort8*)xb + i) = o;
}

// ---------- kernel 3: bf16 GEMM  C[M,N] = A[M,K] * B[N,K]^T + bias ----------
// m97 structure: 128x128 tile, BK=32, 4 waves (2x2), 4x4 frags of 16x16x32 MFMA,
// global_load_lds width=16 staging, single LDS buffer, 2 barriers per K-step.
#define BM 128
#define BN 128
#define BK 32

__global__ void __launch_bounds__(256) gemm_bf16(const unsigned short* __restrict__ A,
                                                 const unsigned short* __restrict__ B,
                                                 const float* __restrict__ bias,
                                                 float* __restrict__ C,
                                                 int M, int N, int K) {
    __shared__ unsigned short sA[BM * BK];   // 8 KB, linear [row][32]
    __shared__ unsigned short sB[BN * BK];   // 8 KB

    const int t  = threadIdx.x;
    const int wv = t >> 6;
    const int ln = t & 63;
    const int lr = ln & 15;    // fragment row/col within 16
    const int lk = ln >> 4;    // k-group 0..3 (8 bf16 each)

    const int m0 = blockIdx.y * BM;
    const int n0 = blockIdx.x * BN;

    // staging coords: thread t loads 16B = 8 bf16 at (row = t/4 [+64], col = (t%4)*8)
    const int srow = t >> 2;
    const int scol = (t & 3) * 8;

    const unsigned short* gA0 = A + (size_t)(m0 + srow) * K + scol;
    const unsigned short* gA1 = A + (size_t)(m0 + 64 + srow) * K + scol;
    const unsigned short* gB0 = B + (size_t)(n0 + srow) * K + scol;
    const unsigned short* gB1 = B + (size_t)(n0 + 64 + srow) * K + scol;

    // wave-uniform LDS bases: HW writes base + lane*16B
    unsigned short* lA0 = sA + wv * 512;
    unsigned short* lA1 = sA + 2048 + wv * 512;
    unsigned short* lB0 = sB + wv * 512;
    unsigned short* lB1 = sB + 2048 + wv * 512;

    const int wr = wv >> 1;    // wave row 0..1 (64 rows each)
    const int wc = wv & 1;     // wave col 0..1

    f32x4 acc[4][4];
#pragma unroll
    for (int mi = 0; mi < 4; ++mi)
#pragma unroll
        for (int ni = 0; ni < 4; ++ni)
            acc[mi][ni] = (f32x4)(0.0f);

    for (int k0 = 0; k0 < K; k0 += BK) {
        GL16(gA0 + k0, lA0);
        GL16(gA1 + k0, lA1);
        GL16(gB0 + k0, lB0);
        GL16(gB1 + k0, lB1);
        __syncthreads();   // compiler drains vmcnt(0) before s_barrier -> tile ready

        bf16x8 af[4], bfr[4];
#pragma unroll
        for (int mi = 0; mi < 4; ++mi)
            af[mi] = *(const bf16x8*)&sA[(wr * 64 + mi * 16 + lr) * BK + lk * 8];
#pragma unroll
        for (int ni = 0; ni < 4; ++ni)
            bfr[ni] = *(const bf16x8*)&sB[(wc * 64 + ni * 16 + lr) * BK + lk * 8];

#pragma unroll
        for (int mi = 0; mi < 4; ++mi)
#pragma unroll
            for (int ni = 0; ni < 4; ++ni)
                acc[mi][ni] = __builtin_amdgcn_mfma_f32_16x16x32_bf16(af[mi], bfr[ni],
                                                                      acc[mi][ni], 0, 0, 0);
        __syncthreads();   // protect LDS from next iteration's staging
    }

    // epilogue: C/D layout col = lane&15, row = (lane>>4)*4 + reg
#pragma unroll
    for (int ni = 0; ni < 4; ++ni) {
        int n = n0 + wc * 64 + ni * 16 + lr;
        float bv = bias[n];
#pragma unroll
        for (int mi = 0; mi < 4; ++mi) {
            int m = m0 + wr * 64 + mi * 16 + lk * 4;
            f32x4 v = acc[mi][ni];
            C[(size_t)(m + 0) * N + n] = v[0] + bv;
            C[(size_t)(m + 1) * N + n] = v[1] + bv;
            C[(size_t)(m + 2) * N + n] = v[2] + bv;
            C[(size_t)(m + 3) * N + n] = v[3] + bv;
        }
    }
}

// ---------- launcher ----------
extern "C" void kernel_launch(void* const* d_in, const int* in_sizes, int n_in,
                              void* d_out, int out_size, void* d_ws, size_t ws_size,
                              hipStream_t stream) {
    const float* x    = (const float*)d_in[0];
    const float* w    = (const float*)d_in[1];
    const float* bias = (const float*)d_in[2];
    float* out        = (float*)d_out;

    const int dout = in_sizes[2];            // 4096
    const int din  = in_sizes[1] / dout;     // 4096
    const int M    = in_sizes[0] / din;      // 8192
    const int N    = dout, K = din;

    unsigned short* xb = (unsigned short*)d_ws;          // [M][K] bf16 bits
    unsigned short* wb = xb + (size_t)M * K;             // [N][K] bf16 bits

    const int ng_w = (N * K) / 8;
    qdq_weight<<<(ng_w + 255) / 256, 256, 0, stream>>>(w, wb, ng_w);

    const int n8_x = (M * K) / 8;
    cvt_bf16<<<(n8_x + 255) / 256, 256, 0, stream>>>(x, xb, n8_x);

    dim3 grid(N / BN, M / BM);
    gemm_bf16<<<grid, 256, 0, stream>>>(xb, wb, bias, out, M, N, K);
}

// Round 2
// 311.445 us; speedup vs baseline: 1.2968x; 1.2968x over previous
//
#include <hip/hip_runtime.h>
#include <hip/hip_bf16.h>
#include <stdint.h>

// ---------- types ----------
typedef __attribute__((ext_vector_type(8))) __bf16 bf16x8;
typedef __attribute__((ext_vector_type(4))) float f32x4;
typedef __attribute__((ext_vector_type(8))) unsigned short ushort8;

typedef const void __attribute__((address_space(1))) gv_t;
typedef void __attribute__((address_space(3))) lv_t;

#define GL16(g, l) __builtin_amdgcn_global_load_lds((gv_t*)(g), (lv_t*)(l), 16, 0, 0)

// f32 -> bf16 bits, round-to-nearest-even
__device__ __forceinline__ unsigned short f2bf(float f) {
    unsigned int u = __float_as_uint(f);
    u += 0x7fffu + ((u >> 16) & 1u);
    return (unsigned short)(u >> 16);
}

// ---------- kernel 1: per-group int4 quant-dequant of W -> bf16 bits ----------
__global__ void __launch_bounds__(256) qdq_weight(const float* __restrict__ w,
                                                  unsigned short* __restrict__ wb,
                                                  int n_groups) {
    int g = blockIdx.x * 256 + threadIdx.x;
    if (g >= n_groups) return;
    const float4* p = (const float4*)w + (size_t)g * 2;
    float4 v0 = p[0], v1 = p[1];
    float t[8] = {v0.x, v0.y, v0.z, v0.w, v1.x, v1.y, v1.z, v1.w};
    float amax = 0.0f;
#pragma unroll
    for (int j = 0; j < 8; ++j) amax = fmaxf(amax, fabsf(t[j]));
    float scale = fmaxf(amax / 7.0f, 1e-8f);
    ushort8 o;
#pragma unroll
    for (int j = 0; j < 8; ++j) {
        float q = rintf(t[j] / scale);
        q = fminf(fmaxf(q, -7.0f), 7.0f);
        o[j] = f2bf(q * scale);
    }
    *((ushort8*)wb + g) = o;
}

// ---------- kernel 2: f32 -> bf16 cast of x ----------
__global__ void __launch_bounds__(256) cvt_bf16(const float* __restrict__ x,
                                                unsigned short* __restrict__ xb,
                                                int n8) {
    int i = blockIdx.x * 256 + threadIdx.x;
    if (i >= n8) return;
    const float4* p = (const float4*)x + (size_t)i * 2;
    float4 v0 = p[0], v1 = p[1];
    ushort8 o;
    o[0] = f2bf(v0.x); o[1] = f2bf(v0.y); o[2] = f2bf(v0.z); o[3] = f2bf(v0.w);
    o[4] = f2bf(v1.x); o[5] = f2bf(v1.y); o[6] = f2bf(v1.z); o[7] = f2bf(v1.w);
    *((ushort8*)xb + i) = o;
}

// ---------- kernel 3: 256x256 8-wave 4-phase bf16 GEMM, C = A * B^T + bias ----------
#define BM 256
#define BN 256
#define BK 64

// 16 MFMA for one C-quadrant (qm, qn) over K=64, wrapped in setprio
#define MFMA_Q(qm, qn, AF, BF)                                                 \
    __builtin_amdgcn_s_setprio(1);                                             \
    _Pragma("unroll")                                                          \
    for (int mi = 0; mi < 4; ++mi)                                             \
        _Pragma("unroll")                                                      \
        for (int ni = 0; ni < 2; ++ni)                                         \
            _Pragma("unroll")                                                  \
            for (int ks = 0; ks < 2; ++ks)                                     \
                acc[(qm) * 4 + mi][(qn) * 2 + ni] =                            \
                    __builtin_amdgcn_mfma_f32_16x16x32_bf16(                   \
                        AF[mi][ks], BF[ni][ks],                                \
                        acc[(qm) * 4 + mi][(qn) * 2 + ni], 0, 0, 0);           \
    __builtin_amdgcn_s_setprio(0);

// stage 256 rows x 64 cols (one K-tile of one matrix): 4 x global_load_lds per thread.
// Global source column chunk is pre-swizzled (chunk ^= row&7) so that linear LDS
// writes produce the swizzled layout the ds_reads expect (involution, rule #21).
#define STAGE4(dst, src, kk)                                                   \
    {                                                                          \
        _Pragma("unroll")                                                      \
        for (int rr = 0; rr < 4; ++rr)                                         \
            GL16((src) + (size_t)(rr * 64 + srow) * K + (kk) + schunk,         \
                 (dst) + rr * 64 * BK + sldso);                                \
    }

__global__ void __launch_bounds__(512, 2)
gemm256(const unsigned short* __restrict__ A,   // [M][K] bf16 bits (x)
        const unsigned short* __restrict__ B,   // [N][K] bf16 bits (w_deq)
        const float* __restrict__ bias,
        float* __restrict__ C,
        int M, int N, int K) {
    __shared__ unsigned short sA[2][BM * BK];   // 2 x 32 KB
    __shared__ unsigned short sB[2][BN * BK];   // 2 x 32 KB  (128 KiB total)

    const int t  = threadIdx.x;
    const int w  = t >> 6;       // wave 0..7
    const int ln = t & 63;
    const int lr = ln & 15;
    const int lk = ln >> 4;
    const int wr = w >> 2;       // wave M index 0..1 (128 rows each)
    const int wc = w & 3;        // wave N index 0..3 (64 cols each)

    // T1: bijective XCD swizzle (gridDim.x % 8 == 0 here)
    const int nbn = N / BN;
    const int bid = blockIdx.x;
    const int swz = ((int)gridDim.x & 7) ? bid
                  : ((bid & 7) * ((int)gridDim.x >> 3) + (bid >> 3));
    const int m0 = (swz / nbn) * BM;
    const int n0 = (swz % nbn) * BN;

    const unsigned short* gA = A + (size_t)m0 * K;
    const unsigned short* gB = B + (size_t)n0 * K;

    // staging coords: thread t covers row (t>>3) of a 64-row round,
    // 16B chunk (t&7) XOR'd with row&7 (pre-swizzled global source)
    const int srow   = t >> 3;
    const int schunk = (((t & 7) ^ (srow & 7)) << 3);   // elements
    const int sldso  = (w * 8) * BK;                    // wave-uniform LDS row base

    // swizzled k-chunk element offsets for ds_read_b128 fragments
    const int sw = (lr & 7) << 3;
    const int e0 = (lk * 8) ^ sw;          // k-step 0
    const int e1 = (32 + lk * 8) ^ sw;     // k-step 1

    f32x4 acc[8][4];
#pragma unroll
    for (int i = 0; i < 8; ++i)
#pragma unroll
        for (int j = 0; j < 4; ++j)
            acc[i][j] = (f32x4)(0.0f);

    const int NT = K / BK;

    // prologue: tile 0 -> buf0, tile 1 -> buf1; wait tile 0 landed (8 newest in flight)
    STAGE4(&sA[0][0], gA, 0);
    STAGE4(&sB[0][0], gB, 0);
    STAGE4(&sA[1][0], gA, BK);
    STAGE4(&sB[1][0], gB, BK);
    asm volatile("s_waitcnt vmcnt(8)" ::: "memory");
    asm volatile("s_barrier" ::: "memory");

    for (int tt = 0; tt < NT; ++tt) {
        const unsigned short* Ls_A = &sA[tt & 1][0];
        const unsigned short* Ls_B = &sB[tt & 1][0];
        unsigned short* Ld_A = &sA[tt & 1][0];
        unsigned short* Ld_B = &sB[tt & 1][0];
        const bool st = (tt + 2 < NT);
        const int k2 = (tt + 2) * BK;

        bf16x8 a0[4][2], a1[4][2], b0[2][2], b1[2][2];

        // ---- phase 1: read A-low + B-low; MFMA quadrant (0,0)
#pragma unroll
        for (int mi = 0; mi < 4; ++mi) {
            const int r = (wr * 128 + mi * 16 + lr) * BK;
            a0[mi][0] = *(const bf16x8*)&Ls_A[r + e0];
            a0[mi][1] = *(const bf16x8*)&Ls_A[r + e1];
        }
#pragma unroll
        for (int ni = 0; ni < 2; ++ni) {
            const int r = (wc * 64 + ni * 16 + lr) * BK;
            b0[ni][0] = *(const bf16x8*)&Ls_B[r + e0];
            b0[ni][1] = *(const bf16x8*)&Ls_B[r + e1];
        }
        __builtin_amdgcn_s_barrier();
        MFMA_Q(0, 0, a0, b0);
        asm volatile("s_barrier" ::: "memory");

        // ---- phase 2: read A-high; MFMA quadrant (1,0)  [B0 dies after]
#pragma unroll
        for (int mi = 0; mi < 4; ++mi) {
            const int r = (wr * 128 + 64 + mi * 16 + lr) * BK;
            a1[mi][0] = *(const bf16x8*)&Ls_A[r + e0];
            a1[mi][1] = *(const bf16x8*)&Ls_A[r + e1];
        }
        __builtin_amdgcn_s_barrier();
        MFMA_Q(1, 0, a1, b0);
        asm volatile("s_barrier" ::: "memory");
        // all A-reads of this buffer are now complete across the block

        // ---- phase 3: read B-high; stage next A-tile into this buffer; MFMA (1,1)
#pragma unroll
        for (int ni = 0; ni < 2; ++ni) {
            const int r = (wc * 64 + 32 + ni * 16 + lr) * BK;
            b1[ni][0] = *(const bf16x8*)&Ls_B[r + e0];
            b1[ni][1] = *(const bf16x8*)&Ls_B[r + e1];
        }
        if (st) STAGE4(Ld_A, gA, k2);
        __builtin_amdgcn_s_barrier();
        MFMA_Q(1, 1, a1, b1);
        asm volatile("s_barrier" ::: "memory");
        // all B-reads of this buffer are now complete across the block

        // ---- phase 4: stage next B-tile; MFMA (0,1); counted tile fence
        if (st) STAGE4(Ld_B, gB, k2);
        __builtin_amdgcn_s_barrier();
        MFMA_Q(0, 1, a0, b1);
        if (st) asm volatile("s_waitcnt vmcnt(8)" ::: "memory");
        else    asm volatile("s_waitcnt vmcnt(0)" ::: "memory");
        asm volatile("s_barrier" ::: "memory");
    }

    // ---- epilogue: C/D layout col = lane&15, row = (lane>>4)*4 + reg
#pragma unroll
    for (int j = 0; j < 4; ++j) {
        const int n = n0 + wc * 64 + (j >> 1) * 32 + (j & 1) * 16 + lr;
        const float bv = bias[n];
#pragma unroll
        for (int i = 0; i < 8; ++i) {
            const int m = m0 + wr * 128 + (i >> 2) * 64 + (i & 3) * 16 + lk * 4;
            f32x4 v = acc[i][j];
            C[(size_t)(m + 0) * N + n] = v[0] + bv;
            C[(size_t)(m + 1) * N + n] = v[1] + bv;
            C[(size_t)(m + 2) * N + n] = v[2] + bv;
            C[(size_t)(m + 3) * N + n] = v[3] + bv;
        }
    }
}

// ---------- launcher ----------
extern "C" void kernel_launch(void* const* d_in, const int* in_sizes, int n_in,
                              void* d_out, int out_size, void* d_ws, size_t ws_size,
                              hipStream_t stream) {
    const float* x    = (const float*)d_in[0];
    const float* wgt  = (const float*)d_in[1];
    const float* bias = (const float*)d_in[2];
    float* out        = (float*)d_out;

    const int dout = in_sizes[2];            // 4096
    const int din  = in_sizes[1] / dout;     // 4096
    const int M    = in_sizes[0] / din;      // 8192
    const int N    = dout, K = din;

    unsigned short* xb = (unsigned short*)d_ws;          // [M][K] bf16 bits
    unsigned short* wb = xb + (size_t)M * K;             // [N][K] bf16 bits

    const int ng_w = (N * K) / 8;
    qdq_weight<<<(ng_w + 255) / 256, 256, 0, stream>>>(wgt, wb, ng_w);

    const int n8_x = (M * K) / 8;
    cvt_bf16<<<(n8_x + 255) / 256, 256, 0, stream>>>(x, xb, n8_x);

    const int nwg = (M / BM) * (N / BN);     // 512, % 8 == 0
    gemm256<<<nwg, 512, 0, stream>>>(xb, wb, bias, out, M, N, K);
}

// Round 3
// 306.796 us; speedup vs baseline: 1.3165x; 1.0152x over previous
//
#include <hip/hip_runtime.h>
#include <hip/hip_bf16.h>
#include <stdint.h>

// ---------- types ----------
typedef __attribute__((ext_vector_type(8))) __bf16 bf16x8;
typedef __attribute__((ext_vector_type(4))) float f32x4;
typedef __attribute__((ext_vector_type(8))) unsigned short ushort8;

typedef const void __attribute__((address_space(1))) gv_t;
typedef void __attribute__((address_space(3))) lv_t;

#define GL16(g, l) __builtin_amdgcn_global_load_lds((gv_t*)(g), (lv_t*)(l), 16, 0, 0)

// f32 -> bf16 bits, round-to-nearest-even
__device__ __forceinline__ unsigned short f2bf(float f) {
    unsigned int u = __float_as_uint(f);
    u += 0x7fffu + ((u >> 16) & 1u);
    return (unsigned short)(u >> 16);
}

// ---------- kernel 1: per-group int4 quant-dequant of W -> bf16 bits ----------
__global__ void __launch_bounds__(256) qdq_weight(const float* __restrict__ w,
                                                  unsigned short* __restrict__ wb,
                                                  int n_groups) {
    int g = blockIdx.x * 256 + threadIdx.x;
    if (g >= n_groups) return;
    const float4* p = (const float4*)w + (size_t)g * 2;
    float4 v0 = p[0], v1 = p[1];
    float t[8] = {v0.x, v0.y, v0.z, v0.w, v1.x, v1.y, v1.z, v1.w};
    float amax = 0.0f;
#pragma unroll
    for (int j = 0; j < 8; ++j) amax = fmaxf(amax, fabsf(t[j]));
    float scale = fmaxf(amax / 7.0f, 1e-8f);
    ushort8 o;
#pragma unroll
    for (int j = 0; j < 8; ++j) {
        float q = rintf(t[j] / scale);
        q = fminf(fmaxf(q, -7.0f), 7.0f);
        o[j] = f2bf(q * scale);
    }
    *((ushort8*)wb + g) = o;
}

// ---------- kernel 2: f32 -> bf16 cast of x ----------
__global__ void __launch_bounds__(256) cvt_bf16(const float* __restrict__ x,
                                                unsigned short* __restrict__ xb,
                                                int n8) {
    int i = blockIdx.x * 256 + threadIdx.x;
    if (i >= n8) return;
    const float4* p = (const float4*)x + (size_t)i * 2;
    float4 v0 = p[0], v1 = p[1];
    ushort8 o;
    o[0] = f2bf(v0.x); o[1] = f2bf(v0.y); o[2] = f2bf(v0.z); o[3] = f2bf(v0.w);
    o[4] = f2bf(v1.x); o[5] = f2bf(v1.y); o[6] = f2bf(v1.z); o[7] = f2bf(v1.w);
    *((ushort8*)xb + i) = o;
}

// ---------- kernel 3: 256x256 8-wave TRUE-8-phase bf16 GEMM, C = A * B^T + bias ----
// Halves interleaved so every wave's frag group lives in one half:
//   A.h = m-rows {h*64..h*64+63} U {128+h*64..128+h*64+63}  (slots 0-127)
//   B.h = n-rows {h*32 + wcblk*64 + r} for wcblk 0..3       (slots 0-127)
// Stage = 2 x global_load_lds per thread per half; one half staged per phase.
// vmcnt(4) at phases 4/8 only (before closing barrier) -> gate via barrier.
#define BM 256
#define BN 256
#define BK 64

#define MFMA_Q(qm, qn, AF, BF)                                                 \
    __builtin_amdgcn_s_setprio(1);                                             \
    _Pragma("unroll")                                                          \
    for (int mi = 0; mi < 4; ++mi)                                             \
        _Pragma("unroll")                                                      \
        for (int ni = 0; ni < 2; ++ni)                                         \
            _Pragma("unroll")                                                  \
            for (int ks = 0; ks < 2; ++ks)                                     \
                acc[(qm) * 4 + mi][(qn) * 2 + ni] =                            \
                    __builtin_amdgcn_mfma_f32_16x16x32_bf16(                   \
                        AF[mi][ks], BF[ni][ks],                                \
                        acc[(qm) * 4 + mi][(qn) * 2 + ni], 0, 0, 0);           \
    __builtin_amdgcn_s_setprio(0);

// A half h of K-tile at column kk -> buf b (2 loads: m-rows h*64+srow, h*64+128+srow)
#define STAGE_A(b, h, kk)                                                      \
    {                                                                          \
        GL16(gA + (size_t)((h) * 64 + srow) * K + (kk) + schunk,               \
             &sA[b][h][0] + sldso);                                            \
        GL16(gA + (size_t)((h) * 64 + 128 + srow) * K + (kk) + schunk,         \
             &sA[b][h][64 * BK] + sldso);                                      \
    }
// B half h (n-rows h*32 + brow [+128]) -> buf b
#define STAGE_B(b, h, kk)                                                      \
    {                                                                          \
        GL16(gB + (size_t)((h) * 32 + brow) * K + (kk) + schunk,               \
             &sB[b][h][0] + sldso);                                            \
        GL16(gB + (size_t)((h) * 32 + 128 + brow) * K + (kk) + schunk,         \
             &sB[b][h][64 * BK] + sldso);                                      \
    }

#define READ_A(dst, b, h)                                                      \
    _Pragma("unroll")                                                          \
    for (int mi = 0; mi < 4; ++mi) {                                           \
        const int s_ = (wr * 64 + mi * 16 + lr) * BK;                          \
        dst[mi][0] = *(const bf16x8*)&sA[b][h][s_ + e0];                       \
        dst[mi][1] = *(const bf16x8*)&sA[b][h][s_ + e1];                       \
    }
#define READ_B(dst, b, h)                                                      \
    _Pragma("unroll")                                                          \
    for (int ni = 0; ni < 2; ++ni) {                                           \
        const int s_ = (bcol + ni * 16 + lr) * BK;                             \
        dst[ni][0] = *(const bf16x8*)&sB[b][h][s_ + e0];                       \
        dst[ni][1] = *(const bf16x8*)&sB[b][h][s_ + e1];                       \
    }

#define OPEN_BAR()  __builtin_amdgcn_s_barrier()
#define CLOSE_BAR() asm volatile("s_barrier" ::: "memory")
#define VM(n)       asm volatile("s_waitcnt vmcnt(" #n ")" ::: "memory")

__global__ void __launch_bounds__(512, 2)
gemm256(const unsigned short* __restrict__ A,   // [M][K] bf16 bits (x)
        const unsigned short* __restrict__ B,   // [N][K] bf16 bits (w_deq)
        const float* __restrict__ bias,
        float* __restrict__ C,
        int M, int N, int K) {
    __shared__ unsigned short sA[2][2][128 * BK];   // 2 buf x 2 half x 16KB
    __shared__ unsigned short sB[2][2][128 * BK];   // 128 KiB total

    const int t  = threadIdx.x;
    const int w  = t >> 6;
    const int ln = t & 63;
    const int lr = ln & 15;
    const int lk = ln >> 4;
    const int wr = w >> 2;                        // wave M index (128 rows)
    const int wc = w & 3;                         // wave N index (64 cols)
    const int bcol = (wc >> 1) * 64 + (wc & 1) * 32;   // B slot base for this wave

    // T1: bijective XCD swizzle (gridDim.x % 8 == 0 here)
    const int nbn = N / BN;
    const int bid = blockIdx.x;
    const int swz = ((int)gridDim.x & 7) ? bid
                  : ((bid & 7) * ((int)gridDim.x >> 3) + (bid >> 3));
    const int m0 = (swz / nbn) * BM;
    const int n0 = (swz % nbn) * BN;

    const unsigned short* gA = A + (size_t)m0 * K;
    const unsigned short* gB = B + (size_t)n0 * K;

    // staging coords (pre-swizzled global source, linear LDS dest)
    const int srow   = t >> 3;                               // 0..63
    const int brow   = (srow & 31) + ((srow >> 5) << 6);     // B interleave
    const int schunk = (((t & 7) ^ (srow & 7)) << 3);        // elements
    const int sldso  = (w * 8) * BK;                         // wave-uniform

    // swizzled ds_read element offsets
    const int sw = (lr & 7) << 3;
    const int e0 = (lk * 8) ^ sw;
    const int e1 = (32 + lk * 8) ^ sw;

    f32x4 acc[8][4];
#pragma unroll
    for (int i = 0; i < 8; ++i)
#pragma unroll
        for (int j = 0; j < 4; ++j)
            acc[i][j] = (f32x4)(0.0f);

    const int NT = K / BK;   // must be even (64 here)

    // prologue: tile0 complete -> buf0; tile1 h0 halves -> buf1 (12 loads)
    STAGE_A(0, 0, 0); STAGE_B(0, 0, 0);
    STAGE_A(0, 1, 0); STAGE_B(0, 1, 0);
    STAGE_A(1, 0, BK); STAGE_B(1, 0, BK);
    VM(4);             // force tile0's 4 halves landed (leave tile1's h0 pair)
    CLOSE_BAR();

    for (int it = 0; it < NT / 2; ++it) {
        const int t0  = 2 * it;
        const int kC  = (t0 + 1) * BK;     // buf1's current tile (h1 halves)
        const int kN0 = (t0 + 2) * BK;     // buf0 next tile
        const int kN1 = (t0 + 3) * BK;     // buf1 next tile
        const bool st = (t0 + 2 < NT);     // == (t0+3 < NT) for even NT

        bf16x8 a0[4][2], a1[4][2], b0[2][2], b1[2][2];

        // ph1: reads a0,b0 (buf0); stage buf1.A.h1 (tile t0+1); Q00
        READ_A(a0, 0, 0); READ_B(b0, 0, 0);
        STAGE_A(1, 1, kC);
        OPEN_BAR();
        MFMA_Q(0, 0, a0, b0);
        CLOSE_BAR();

        // ph2: read a1; stage buf1.B.h1; Q10
        READ_A(a1, 0, 1);
        STAGE_B(1, 1, kC);
        OPEN_BAR();
        MFMA_Q(1, 0, a1, b0);
        CLOSE_BAR();

        // ph3: read b1; stage buf0.A.h0 (next); Q11
        READ_B(b1, 0, 1);
        if (st) STAGE_A(0, 0, kN0);
        OPEN_BAR();
        MFMA_Q(1, 1, a1, b1);
        CLOSE_BAR();

        // ph4: stage buf0.B.h0 (next); Q01; counted gate for ph5-7 reads
        if (st) STAGE_B(0, 0, kN0);
        OPEN_BAR();
        MFMA_Q(0, 1, a0, b1);
        if (st) VM(4); else VM(0);
        CLOSE_BAR();

        // ph5: reads a0,b0 (buf1); stage buf0.A.h1 (next); Q00
        READ_A(a0, 1, 0); READ_B(b0, 1, 0);
        if (st) STAGE_A(0, 1, kN0);
        OPEN_BAR();
        MFMA_Q(0, 0, a0, b0);
        CLOSE_BAR();

        // ph6: read a1; stage buf0.B.h1 (next); Q10
        READ_A(a1, 1, 1);
        if (st) STAGE_B(0, 1, kN0);
        OPEN_BAR();
        MFMA_Q(1, 0, a1, b0);
        CLOSE_BAR();

        // ph7: read b1; stage buf1.A.h0 (next-next); Q11
        READ_B(b1, 1, 1);
        if (st) STAGE_A(1, 0, kN1);
        OPEN_BAR();
        MFMA_Q(1, 1, a1, b1);
        CLOSE_BAR();

        // ph8: stage buf1.B.h0 (next-next); Q01; counted gate for next ph1-3 reads
        if (st) STAGE_B(1, 0, kN1);
        OPEN_BAR();
        MFMA_Q(0, 1, a0, b1);
        if (st) VM(4); else VM(0);
        CLOSE_BAR();
    }

    // epilogue: C/D layout col = lane&15, row = (lane>>4)*4 + reg
#pragma unroll
    for (int j = 0; j < 4; ++j) {
        const int n = n0 + wc * 64 + (j >> 1) * 32 + (j & 1) * 16 + lr;
        const float bv = bias[n];
#pragma unroll
        for (int i = 0; i < 8; ++i) {
            const int m = m0 + wr * 128 + (i >> 2) * 64 + (i & 3) * 16 + lk * 4;
            f32x4 v = acc[i][j];
            C[(size_t)(m + 0) * N + n] = v[0] + bv;
            C[(size_t)(m + 1) * N + n] = v[1] + bv;
            C[(size_t)(m + 2) * N + n] = v[2] + bv;
            C[(size_t)(m + 3) * N + n] = v[3] + bv;
        }
    }
}

// ---------- launcher ----------
extern "C" void kernel_launch(void* const* d_in, const int* in_sizes, int n_in,
                              void* d_out, int out_size, void* d_ws, size_t ws_size,
                              hipStream_t stream) {
    const float* x    = (const float*)d_in[0];
    const float* wgt  = (const float*)d_in[1];
    const float* bias = (const float*)d_in[2];
    float* out        = (float*)d_out;

    const int dout = in_sizes[2];            // 4096
    const int din  = in_sizes[1] / dout;     // 4096
    const int M    = in_sizes[0] / din;      // 8192
    const int N    = dout, K = din;

    unsigned short* xb = (unsigned short*)d_ws;          // [M][K] bf16 bits
    unsigned short* wb = xb + (size_t)M * K;             // [N][K] bf16 bits

    const int ng_w = (N * K) / 8;
    qdq_weight<<<(ng_w + 255) / 256, 256, 0, stream>>>(wgt, wb, ng_w);

    const int n8_x = (M * K) / 8;
    cvt_bf16<<<(n8_x + 255) / 256, 256, 0, stream>>>(x, xb, n8_x);

    const int nwg = (M / BM) * (N / BN);     // 512, % 8 == 0
    gemm256<<<nwg, 512, 0, stream>>>(xb, wb, bias, out, M, N, K);
}